// Round 9
// baseline (199.974 us; speedup 1.0000x reference)
//
#include <hip/hip_runtime.h>
#include <stdint.h>
#include <math.h>

// MulHeadAttn on MI355X. B=2, C=1024, E=1024, head_dim(H)=16, n_heads(HD)=64.
// cast(fp32->bf16, Wq pre-scaled 0.25*log2e) -> fused QKV bf16-MFMA GEMM
// (64x128 tile, BK=64, padded LDS) -> MFMA flash attention (no-max softmax
// in exp2 domain; transposed QK; double-buffered K/V + register prefetch,
// one barrier per tile) -> bf16-MFMA O-projection.

typedef __bf16   bf16x8 __attribute__((ext_vector_type(8)));
typedef float    f32x4  __attribute__((ext_vector_type(4)));

__device__ __forceinline__ unsigned short f2bf(float f) {
    unsigned int u = __float_as_uint(f);
    u += 0x7FFFu + ((u >> 16) & 1u);         // round-to-nearest-even
    return (unsigned short)(u >> 16);
}
__device__ __forceinline__ float bflo(unsigned int u) { return __uint_as_float(u << 16); }

// pack two fp32 -> two bf16 (round-nearest-ties-away): 2 adds + 1 v_perm
__device__ __forceinline__ unsigned int pkbf(float lo, float hi) {
    const unsigned int ulo = __float_as_uint(lo) + 0x8000u;
    const unsigned int uhi = __float_as_uint(hi) + 0x8000u;
    return __builtin_amdgcn_perm(uhi, ulo, 0x07060302u);  // [uhi.hi16 | ulo.hi16]
}

// ---------------------------------------------------------------- cast ----
// z=0,1: halves of x; z=2: Wq scaled 0.25*log2(e); z=3..5: Wk, Wv, Wo.
__global__ __launch_bounds__(256) void cast_to_bf16(
    const float* __restrict__ x,
    const float* __restrict__ w0, const float* __restrict__ w1,
    const float* __restrict__ w2, const float* __restrict__ w3,
    unsigned short* __restrict__ xb,
    unsigned short* __restrict__ b0, unsigned short* __restrict__ b1,
    unsigned short* __restrict__ b2, unsigned short* __restrict__ b3)
{
    const int z = blockIdx.y;
    const float* src;
    unsigned short* dst;
    size_t off = 0;
    float sc = 1.f;
    if (z < 2)       { src = x;  dst = xb; off = (size_t)z << 20; }
    else if (z == 2) { src = w0; dst = b0; sc = 0.36067376022224085f; } // 0.25*log2e
    else if (z == 3) { src = w1; dst = b1; }
    else if (z == 4) { src = w2; dst = b2; }
    else             { src = w3; dst = b3; }
    const size_t i = off + ((size_t)blockIdx.x * 256 + threadIdx.x) * 4;
    const float4 v = *(const float4*)(src + i);
    *(ushort4*)(dst + i) = make_ushort4(f2bf(v.x * sc), f2bf(v.y * sc),
                                        f2bf(v.z * sc), f2bf(v.w * sc));
}

// ---------------------------------------------------------------- GEMM ----
// C[m,n] = sum_k A[m,k]*Bmat[n,k]  (NT), bf16 in, fp32 acc.
// 64x128 tile, BK=64 (R9: halves barrier count; 16 MFMA/wave per barrier).
// LDS stride 72 (144 B) -> frag-read banks (4row+4kg)%32, 2-way max = free.
// Staging: A 2 slots + B 4 slots per thread (b128), register-prefetched.
#define ASTR 72

__global__ __launch_bounds__(256) void gemm_bt_mfma(
    const unsigned short* __restrict__ A,
    const unsigned short* __restrict__ B0, const unsigned short* __restrict__ B1,
    const unsigned short* __restrict__ B2,
    void* __restrict__ C0, void* __restrict__ C1, void* __restrict__ C2,
    int M, int N, int K, int bf16out)
{
    const unsigned short* Bm = (blockIdx.z == 0) ? B0 : (blockIdx.z == 1) ? B1 : B2;
    void* Cm                 = (blockIdx.z == 0) ? C0 : (blockIdx.z == 1) ? C1 : C2;

    __shared__ __align__(16) unsigned short As[64 * ASTR];    //  9.2 KB
    __shared__ __align__(16) unsigned short Bs[128 * ASTR];   // 18.4 KB

    const int t    = threadIdx.x;
    const int lane = t & 63;
    const int w    = t >> 6;
    const int m0   = blockIdx.y * 64;
    const int n0   = blockIdx.x * 128;
    const int wm   = (w & 1) * 32;
    const int wn   = (w >> 1) * 64;

    // A: 512 b128 slots (64 rows x 8), thread t -> slots t, t+256
    // B: 1024 slots (128 rows x 8), thread t -> slots t+256j, j=0..3
    const int ar0 = t >> 3,           ac0 = (t & 7) * 8;
    const int ar1 = (t + 256) >> 3,   ac1 = ac0;
    const unsigned short* Ap0 = A + (size_t)(m0 + ar0) * K + ac0;
    const unsigned short* Ap1 = A + (size_t)(m0 + ar1) * K + ac1;
    const unsigned short* Bp[4];
    int br[4], bc[4];
#pragma unroll
    for (int j = 0; j < 4; ++j) {
        const int s = t + 256 * j;
        br[j] = s >> 3; bc[j] = (s & 7) * 8;
        Bp[j] = Bm + (size_t)(n0 + br[j]) * K + bc[j];
    }

    f32x4 acc[2][4];
#pragma unroll
    for (int i = 0; i < 2; ++i)
#pragma unroll
        for (int j = 0; j < 4; ++j) acc[i][j] = (f32x4){0.f, 0.f, 0.f, 0.f};

    const int fm = lane & 15;
    const int kg = lane >> 4;

    uint4 ra0 = *(const uint4*)(Ap0);
    uint4 ra1 = *(const uint4*)(Ap1);
    uint4 rb[4];
#pragma unroll
    for (int j = 0; j < 4; ++j) rb[j] = *(const uint4*)(Bp[j]);

    for (int k0 = 0; k0 < K; k0 += 64) {
        if (k0) __syncthreads();
        *(uint4*)&As[ar0 * ASTR + ac0] = ra0;
        *(uint4*)&As[ar1 * ASTR + ac1] = ra1;
#pragma unroll
        for (int j = 0; j < 4; ++j)
            *(uint4*)&Bs[br[j] * ASTR + bc[j]] = rb[j];
        __syncthreads();

        if (k0 + 64 < K) {
            ra0 = *(const uint4*)(Ap0 + k0 + 64);
            ra1 = *(const uint4*)(Ap1 + k0 + 64);
#pragma unroll
            for (int j = 0; j < 4; ++j) rb[j] = *(const uint4*)(Bp[j] + k0 + 64);
        }

#pragma unroll
        for (int ks = 0; ks < 2; ++ks) {
            bf16x8 af[2], bfr[4];
#pragma unroll
            for (int im = 0; im < 2; ++im)
                af[im] = *(const bf16x8*)&As[(wm + im * 16 + fm) * ASTR + ks * 32 + kg * 8];
#pragma unroll
            for (int in = 0; in < 4; ++in)
                bfr[in] = *(const bf16x8*)&Bs[(wn + in * 16 + fm) * ASTR + ks * 32 + kg * 8];
#pragma unroll
            for (int im = 0; im < 2; ++im)
#pragma unroll
                for (int in = 0; in < 4; ++in)
                    acc[im][in] = __builtin_amdgcn_mfma_f32_16x16x32_bf16(
                        af[im], bfr[in], acc[im][in], 0, 0, 0);
        }
    }

    // C/D: col = lane&15, row = (lane>>4)*4 + reg   [m89/m91-verified]
#pragma unroll
    for (int im = 0; im < 2; ++im) {
#pragma unroll
        for (int in = 0; in < 4; ++in) {
            const int row = m0 + wm + im * 16 + kg * 4;
            const int col = n0 + wn + in * 16 + fm;
            if (bf16out) {
                unsigned short* cp = (unsigned short*)Cm;
#pragma unroll
                for (int r = 0; r < 4; ++r)
                    cp[(size_t)(row + r) * N + col] = f2bf(acc[im][in][r]);
            } else {
                float* cp = (float*)Cm;
#pragma unroll
                for (int r = 0; r < 4; ++r)
                    cp[(size_t)(row + r) * N + col] = acc[im][in][r];
            }
        }
    }
}

// ----------------------------------------------------------- attention ----
// grid (8, 128): one block = one (b,hd) x 128 q-rows = 1024 blocks (4/CU).
// R9: K/V double-buffered in LDS + register prefetch -> ONE barrier per
// 64-key tile (was 2), global latency hidden under the previous tile's
// compute. 4 waves; wave wq owns q-rows [wq*32, wq*32+32).
#define KSTR2 40
#define VSTR2 72
#define PSTR  80

__global__ __launch_bounds__(256) void attn_mfma(
    const unsigned short* __restrict__ Qb, const unsigned short* __restrict__ Kb,
    const unsigned short* __restrict__ Vb, unsigned short* __restrict__ Ob)
{
    __shared__ __align__(16) unsigned short Ks[2][64 * KSTR2];   // 10.0 KB
    __shared__ __align__(16) unsigned short VsT[2][16 * VSTR2];  //  4.6 KB
    __shared__ __align__(16) unsigned short Ps[128 * PSTR];      // 20.0 KB
    __shared__ __align__(16) float Lsh[128];                     //  0.5 KB

    const int t    = threadIdx.x;
    const int lane = t & 63;
    const int wq   = t >> 6;
    const int fm   = lane & 15;
    const int kg   = lane >> 4;
    const int bh   = blockIdx.y;
    const size_t base = ((size_t)(bh >> 6) * 1024) * 1024 + (size_t)(bh & 63) * 16;
    const int q0 = blockIdx.x * 128;

    // staging role (fixed per thread): t<128 -> K row t>>1, seg t&1;
    // t>=128 -> V key (t-128)>>1, half (t-128)&1
    const int krow = t >> 1,        kseg = t & 1;
    const int vkey = (t - 128) >> 1, vhalf = (t - 128) & 1;

    // zero the K k-pad in both buffers (real cols rewritten per tile)
    if (t < 128) {
        *(uint4*)&Ks[0][krow * KSTR2 + 16 + kseg * 8] = make_uint4(0, 0, 0, 0);
        *(uint4*)&Ks[1][krow * KSTR2 + 16 + kseg * 8] = make_uint4(0, 0, 0, 0);
    }

    // Q fragments (B-operand): row q0+wq*32+m*16+fm, k=kg*8 (zero kg>=2)
    union { uint4 u; bf16x8 h; } zz; zz.u = make_uint4(0, 0, 0, 0);
    bf16x8 aq[2];
#pragma unroll
    for (int m = 0; m < 2; ++m) {
        if (kg < 2)
            aq[m] = *(const bf16x8*)(Qb + base +
                     (size_t)(q0 + wq * 32 + m * 16 + fm) * 1024 + kg * 8);
        else
            aq[m] = zz.h;
    }

    f32x4 oacc[2];
    float lp[2];
#pragma unroll
    for (int m = 0; m < 2; ++m) {
        oacc[m] = (f32x4){0.f, 0.f, 0.f, 0.f};
        lp[m] = 0.f;
    }

    // prologue: tile 0 -> regs -> buf 0
    uint4 rkv;
    if (t < 128)
        rkv = *(const uint4*)(Kb + base + (size_t)krow * 1024 + kseg * 8);
    else
        rkv = *(const uint4*)(Vb + base + (size_t)vkey * 1024 + vhalf * 8);

    if (t < 128) {
        *(uint4*)&Ks[0][krow * KSTR2 + kseg * 8] = rkv;
    } else {
        const unsigned short* pv = (const unsigned short*)&rkv;
#pragma unroll
        for (int d = 0; d < 8; ++d)
            VsT[0][(vhalf * 8 + d) * VSTR2 + vkey] = pv[d];
    }
    __syncthreads();

    for (int it = 0; it < 16; ++it) {
        const int cur = it & 1;

        // prefetch next tile into regs (latency hidden under compute)
        if (it < 15) {
            const int kt = (it + 1) * 64;
            if (t < 128)
                rkv = *(const uint4*)(Kb + base + (size_t)(kt + krow) * 1024 + kseg * 8);
            else
                rkv = *(const uint4*)(Vb + base + (size_t)(kt + vkey) * 1024 + vhalf * 8);
        }

        // ---- compute on buf cur ----
        bf16x8 bk[4];
#pragma unroll
        for (int kn = 0; kn < 4; ++kn)
            bk[kn] = *(const bf16x8*)&Ks[cur][(kn * 16 + fm) * KSTR2 + kg * 8];

#pragma unroll
        for (int kn = 0; kn < 4; ++kn) {
            f32x4 sm[2];
#pragma unroll
            for (int m = 0; m < 2; ++m)
                sm[m] = __builtin_amdgcn_mfma_f32_16x16x32_bf16(
                    bk[kn], aq[m], (f32x4){0.f, 0.f, 0.f, 0.f}, 0, 0, 0);
#pragma unroll
            for (int m = 0; m < 2; ++m) {
                const float p0 = __builtin_amdgcn_exp2f(sm[m][0]);
                const float p1 = __builtin_amdgcn_exp2f(sm[m][1]);
                const float p2 = __builtin_amdgcn_exp2f(sm[m][2]);
                const float p3 = __builtin_amdgcn_exp2f(sm[m][3]);
                lp[m] += (p0 + p1) + (p2 + p3);
                *(uint2*)&Ps[(wq * 32 + m * 16 + fm) * PSTR + kn * 16 + kg * 4] =
                    make_uint2(pkbf(p0, p1), pkbf(p2, p3));
            }
        }

        bf16x8 bv0 = *(const bf16x8*)&VsT[cur][fm * VSTR2 + kg * 8];
        bf16x8 bv1 = *(const bf16x8*)&VsT[cur][fm * VSTR2 + 32 + kg * 8];
#pragma unroll
        for (int m = 0; m < 2; ++m) {
            const int prow = wq * 32 + m * 16 + fm;
            bf16x8 ap0 = *(const bf16x8*)&Ps[prow * PSTR + kg * 8];
            bf16x8 ap1 = *(const bf16x8*)&Ps[prow * PSTR + 32 + kg * 8];
            oacc[m] = __builtin_amdgcn_mfma_f32_16x16x32_bf16(ap0, bv0, oacc[m], 0, 0, 0);
            oacc[m] = __builtin_amdgcn_mfma_f32_16x16x32_bf16(ap1, bv1, oacc[m], 0, 0, 0);
        }

        // ---- write next tile to buf cur^1 (its readers finished at the
        // barrier that ended iter it-1) ----
        if (it < 15) {
            if (t < 128) {
                *(uint4*)&Ks[cur ^ 1][krow * KSTR2 + kseg * 8] = rkv;
            } else {
                const unsigned short* pv = (const unsigned short*)&rkv;
#pragma unroll
                for (int d = 0; d < 8; ++d)
                    VsT[cur ^ 1][(vhalf * 8 + d) * VSTR2 + vkey] = pv[d];
            }
        }
        __syncthreads();
    }

    // l: sum the 4 kg-group partials, transpose via LDS (wave-local)
#pragma unroll
    for (int m = 0; m < 2; ++m) {
        float v = lp[m];
        v += __shfl_xor(v, 16, 64);
        v += __shfl_xor(v, 32, 64);
        if (kg == 0) Lsh[wq * 32 + m * 16 + fm] = v;
    }

    // epilogue: C-layout rows = q (kg*4+r), cols = d (fm)
#pragma unroll
    for (int m = 0; m < 2; ++m) {
        const float4 lr = *(const float4*)&Lsh[wq * 32 + m * 16 + kg * 4];
        const int qrow = q0 + wq * 32 + m * 16 + kg * 4;
        Ob[base + (size_t)(qrow + 0) * 1024 + fm] = f2bf(oacc[m][0] / lr.x);
        Ob[base + (size_t)(qrow + 1) * 1024 + fm] = f2bf(oacc[m][1] / lr.y);
        Ob[base + (size_t)(qrow + 2) * 1024 + fm] = f2bf(oacc[m][2] / lr.z);
        Ob[base + (size_t)(qrow + 3) * 1024 + fm] = f2bf(oacc[m][3] / lr.w);
    }
}

// -------------------------------------------------------------- launch ----
extern "C" void kernel_launch(void* const* d_in, const int* in_sizes, int n_in,
                              void* d_out, int out_size, void* d_ws, size_t ws_size,
                              hipStream_t stream) {
    const float* x  = (const float*)d_in[0];
    const float* Wq = (const float*)d_in[1];
    const float* Wk = (const float*)d_in[2];
    const float* Wv = (const float*)d_in[3];
    const float* Wo = (const float*)d_in[4];
    float* out = (float*)d_out;

    const int M = 2048, N = 1024, Kd = 1024;
    const size_t MEG = 1048576;
    unsigned short* ws = (unsigned short*)d_ws;   // 28 MB high-water
    unsigned short* xb  = ws;
    unsigned short* Wqb = ws + 2 * MEG;
    unsigned short* Wkb = ws + 3 * MEG;
    unsigned short* Wvb = ws + 4 * MEG;
    unsigned short* Wob = ws + 5 * MEG;
    unsigned short* Qb  = ws + 6 * MEG;
    unsigned short* Kb  = ws + 8 * MEG;
    unsigned short* Vb  = ws + 10 * MEG;
    unsigned short* Ob  = ws + 12 * MEG;

    dim3 gc(1024, 6, 1);
    cast_to_bf16<<<gc, 256, 0, stream>>>(x, Wq, Wk, Wv, Wo, xb, Wqb, Wkb, Wvb, Wob);

    dim3 g1(N / 128, M / 64, 3);
    gemm_bt_mfma<<<g1, 256, 0, stream>>>(xb, Wqb, Wkb, Wvb, Qb, Kb, Vb, M, N, Kd, 1);

    dim3 g2(8, 128, 1);
    attn_mfma<<<g2, 256, 0, stream>>>(Qb, Kb, Vb, Ob);

    dim3 g3(N / 128, M / 64, 1);
    gemm_bt_mfma<<<g3, 256, 0, stream>>>(Ob, Wob, Wob, Wob, out, out, out, M, N, Kd, 0);
}

// Round 10
// 150.489 us; speedup vs baseline: 1.3288x; 1.3288x over previous
//
#include <hip/hip_runtime.h>
#include <stdint.h>
#include <math.h>

// MulHeadAttn on MI355X. B=2, C=1024, E=1024, head_dim(H)=16, n_heads(HD)=64.
// cast(fp32->bf16, Wq pre-scaled 0.25*log2e) -> fused QKV bf16-MFMA GEMM
// (R8 K-loop: BK=32, stride-32 LDS; R10: coalesced bf16 epilogue via LDS
// round-trip, fixes 6x WRITE_SIZE amplification seen in R9 counters) ->
// MFMA flash attention (R8 version: exp2-domain no-max softmax, transposed
// QK, v_perm P-pack, grid 8x128) -> bf16-MFMA O-projection.

typedef __bf16   bf16x8 __attribute__((ext_vector_type(8)));
typedef float    f32x4  __attribute__((ext_vector_type(4)));

__device__ __forceinline__ unsigned short f2bf(float f) {
    unsigned int u = __float_as_uint(f);
    u += 0x7FFFu + ((u >> 16) & 1u);         // round-to-nearest-even
    return (unsigned short)(u >> 16);
}
__device__ __forceinline__ float bflo(unsigned int u) { return __uint_as_float(u << 16); }

// pack two fp32 -> two bf16 (round-nearest-ties-away): 2 adds + 1 v_perm
__device__ __forceinline__ unsigned int pkbf(float lo, float hi) {
    const unsigned int ulo = __float_as_uint(lo) + 0x8000u;
    const unsigned int uhi = __float_as_uint(hi) + 0x8000u;
    return __builtin_amdgcn_perm(uhi, ulo, 0x07060302u);  // [uhi.hi16 | ulo.hi16]
}

// ---------------------------------------------------------------- cast ----
// z=0,1: halves of x; z=2: Wq scaled 0.25*log2(e); z=3..5: Wk, Wv, Wo.
__global__ __launch_bounds__(256) void cast_to_bf16(
    const float* __restrict__ x,
    const float* __restrict__ w0, const float* __restrict__ w1,
    const float* __restrict__ w2, const float* __restrict__ w3,
    unsigned short* __restrict__ xb,
    unsigned short* __restrict__ b0, unsigned short* __restrict__ b1,
    unsigned short* __restrict__ b2, unsigned short* __restrict__ b3)
{
    const int z = blockIdx.y;
    const float* src;
    unsigned short* dst;
    size_t off = 0;
    float sc = 1.f;
    if (z < 2)       { src = x;  dst = xb; off = (size_t)z << 20; }
    else if (z == 2) { src = w0; dst = b0; sc = 0.36067376022224085f; } // 0.25*log2e
    else if (z == 3) { src = w1; dst = b1; }
    else if (z == 4) { src = w2; dst = b2; }
    else             { src = w3; dst = b3; }
    const size_t i = off + ((size_t)blockIdx.x * 256 + threadIdx.x) * 4;
    const float4 v = *(const float4*)(src + i);
    *(ushort4*)(dst + i) = make_ushort4(f2bf(v.x * sc), f2bf(v.y * sc),
                                        f2bf(v.z * sc), f2bf(v.w * sc));
}

// ---------------------------------------------------------------- GEMM ----
// C[m,n] = sum_k A[m,k]*Bmat[n,k]  (NT), bf16 in, fp32 acc. 64x128 tile,
// BK=32 (R8 K-loop, verified). bf16 output: LDS round-trip epilogue ->
// 128 B/row coalesced dwordx4 stores (R9 counters showed 6x write
// amplification from 2-byte scalar stores). f32 output: direct stores
// (64 B/instr segments, no amplification).
#define CSTR 68   // epilogue LDS row stride (ushorts): b16 write banks 2-way max

__global__ __launch_bounds__(256) void gemm_bt_mfma(
    const unsigned short* __restrict__ A,
    const unsigned short* __restrict__ B0, const unsigned short* __restrict__ B1,
    const unsigned short* __restrict__ B2,
    void* __restrict__ C0, void* __restrict__ C1, void* __restrict__ C2,
    int M, int N, int K, int bf16out)
{
    const unsigned short* Bm = (blockIdx.z == 0) ? B0 : (blockIdx.z == 1) ? B1 : B2;
    void* Cm                 = (blockIdx.z == 0) ? C0 : (blockIdx.z == 1) ? C1 : C2;

    // 8704 ushorts = 17 KB: staging (As 2048 + Bs 4096) and the per-wave
    // epilogue regions (4 x 32x68 = 8704) alias; a barrier separates uses.
    __shared__ __align__(16) unsigned short smem[8704];
    unsigned short* As = smem;          // [m][k] stride 32, 64 rows
    unsigned short* Bs = smem + 2048;   // [n][k] stride 32, 128 rows

    const int t    = threadIdx.x;
    const int lane = t & 63;
    const int w    = t >> 6;
    const int m0   = blockIdx.y * 64;
    const int n0   = blockIdx.x * 128;
    const int wm   = (w & 1) * 32;
    const int wn   = (w >> 1) * 64;

    const int r0 = t >> 2;            // 0..63
    const int c0 = (t & 3) * 8;       // k-offset 0,8,16,24
    const unsigned short* Apa = A  + (size_t)(m0 + r0) * K + c0;
    const unsigned short* Bpa = Bm + (size_t)(n0 + r0) * K + c0;
    const unsigned short* Bpb = Bm + (size_t)(n0 + r0 + 64) * K + c0;

    f32x4 acc[2][4];
#pragma unroll
    for (int i = 0; i < 2; ++i)
#pragma unroll
        for (int j = 0; j < 4; ++j) acc[i][j] = (f32x4){0.f, 0.f, 0.f, 0.f};

    const int fm = lane & 15;
    const int kg = lane >> 4;

    uint4 ra0 = *(const uint4*)(Apa);
    uint4 rb0 = *(const uint4*)(Bpa);
    uint4 rb1 = *(const uint4*)(Bpb);

    for (int k0 = 0; k0 < K; k0 += 32) {
        if (k0) __syncthreads();
        *(uint4*)&As[8 * t]        = ra0;
        *(uint4*)&Bs[8 * t]        = rb0;
        *(uint4*)&Bs[8 * t + 2048] = rb1;
        __syncthreads();

        if (k0 + 32 < K) {
            ra0 = *(const uint4*)(Apa + k0 + 32);
            rb0 = *(const uint4*)(Bpa + k0 + 32);
            rb1 = *(const uint4*)(Bpb + k0 + 32);
        }

        bf16x8 af[2], bfr[4];
#pragma unroll
        for (int im = 0; im < 2; ++im)
            af[im] = *(const bf16x8*)&As[(wm + im * 16 + fm) * 32 + kg * 8];
#pragma unroll
        for (int in = 0; in < 4; ++in)
            bfr[in] = *(const bf16x8*)&Bs[(wn + in * 16 + fm) * 32 + kg * 8];
#pragma unroll
        for (int im = 0; im < 2; ++im)
#pragma unroll
            for (int in = 0; in < 4; ++in)
                acc[im][in] = __builtin_amdgcn_mfma_f32_16x16x32_bf16(
                    af[im], bfr[in], acc[im][in], 0, 0, 0);
    }

    // C/D: col = lane&15, row = (lane>>4)*4 + reg   [m89/m91-verified]
    if (bf16out) {
        // --- R10 coalesced epilogue: per-wave 32x64 tile through LDS ---
        __syncthreads();                      // staging readers all done
        unsigned short* R = smem + w * 2176;  // 32 rows x CSTR
        unsigned short* cp = (unsigned short*)Cm;
#pragma unroll
        for (int im = 0; im < 2; ++im)
#pragma unroll
            for (int in = 0; in < 4; ++in)
#pragma unroll
                for (int r = 0; r < 4; ++r)
                    R[(im * 16 + kg * 4 + r) * CSTR + in * 16 + fm] =
                        f2bf(acc[im][in][r]);
        // wave-local read-back (compiler inserts the lgkmcnt wait)
#pragma unroll
        for (int j = 0; j < 4; ++j) {
            const int rr = j * 8 + (lane >> 3);
            const int cc = (lane & 7) * 8;
            const uint4 v = *(const uint4*)&R[rr * CSTR + cc];
            *(uint4*)(cp + (size_t)(m0 + wm + rr) * N + n0 + wn + cc) = v;
        }
    } else {
#pragma unroll
        for (int im = 0; im < 2; ++im) {
#pragma unroll
            for (int in = 0; in < 4; ++in) {
                const int row = m0 + wm + im * 16 + kg * 4;
                const int col = n0 + wn + in * 16 + fm;
                float* cp = (float*)Cm;
#pragma unroll
                for (int r = 0; r < 4; ++r)
                    cp[(size_t)(row + r) * N + col] = acc[im][in][r];
            }
        }
    }
}

// ----------------------------------------------------------- attention ----
// (exact R8 version — 1024 blocks = 4/CU, transposed QK, exp2 softmax,
//  v_perm P-pack; R9's dbuf variant regressed and was reverted)
#define KSTR2 40
#define VSTR2 72
#define PSTR  80

__global__ __launch_bounds__(256) void attn_mfma(
    const unsigned short* __restrict__ Qb, const unsigned short* __restrict__ Kb,
    const unsigned short* __restrict__ Vb, unsigned short* __restrict__ Ob)
{
    __shared__ __align__(16) unsigned short Ks[64 * KSTR2];    //  5.0 KB
    __shared__ __align__(16) unsigned short VsT[16 * VSTR2];   //  2.3 KB
    __shared__ __align__(16) unsigned short Ps[128 * PSTR];    // 20.0 KB
    __shared__ __align__(16) float Lsh[128];                   //  0.5 KB

    const int t    = threadIdx.x;
    const int lane = t & 63;
    const int wq   = t >> 6;
    const int fm   = lane & 15;
    const int kg   = lane >> 4;
    const int bh   = blockIdx.y;
    const size_t base = ((size_t)(bh >> 6) * 1024) * 1024 + (size_t)(bh & 63) * 16;
    const int q0 = blockIdx.x * 128;

    // zero the K k-pad once (real cols rewritten per tile, pad never)
    if (t < 128) {
        const int row = t >> 1, seg = t & 1;
        *(uint4*)&Ks[row * KSTR2 + 16 + seg * 8] = make_uint4(0, 0, 0, 0);
    }

    // Q fragments (B-operand): row q0+wq*32+m*16+fm, k=kg*8 (zero kg>=2)
    union { uint4 u; bf16x8 h; } zz; zz.u = make_uint4(0, 0, 0, 0);
    bf16x8 aq[2];
#pragma unroll
    for (int m = 0; m < 2; ++m) {
        if (kg < 2)
            aq[m] = *(const bf16x8*)(Qb + base +
                     (size_t)(q0 + wq * 32 + m * 16 + fm) * 1024 + kg * 8);
        else
            aq[m] = zz.h;
    }

    f32x4 oacc[2];
    float lp[2];
#pragma unroll
    for (int m = 0; m < 2; ++m) {
        oacc[m] = (f32x4){0.f, 0.f, 0.f, 0.f};
        lp[m] = 0.f;
    }

    for (int kt = 0; kt < 1024; kt += 64) {
        __syncthreads();
        if (t < 128) {           // K tile: 64 rows x 16 real bf16
            const int row = t >> 1, seg = t & 1;
            *(uint4*)&Ks[row * KSTR2 + seg * 8] =
                *(const uint4*)(Kb + base + (size_t)(kt + row) * 1024 + seg * 8);
        } else {                 // V tile, transposed: VsT[d][key]
            const int idx = t - 128;
            const int key = idx >> 1, half = idx & 1;
            uint4 v = *(const uint4*)(Vb + base + (size_t)(kt + key) * 1024 + half * 8);
            const unsigned short* pv = (const unsigned short*)&v;
#pragma unroll
            for (int d = 0; d < 8; ++d)
                VsT[(half * 8 + d) * VSTR2 + key] = pv[d];
        }
        __syncthreads();

        // K fragments (A-operand): row kn*16+fm, k=kg*8
        bf16x8 bk[4];
#pragma unroll
        for (int kn = 0; kn < 4; ++kn)
            bk[kn] = *(const bf16x8*)&Ks[(kn * 16 + fm) * KSTR2 + kg * 8];

        // ---- transposed QK + exp2 + packed b64 P-store
#pragma unroll
        for (int kn = 0; kn < 4; ++kn) {
            f32x4 sm[2];
#pragma unroll
            for (int m = 0; m < 2; ++m)
                sm[m] = __builtin_amdgcn_mfma_f32_16x16x32_bf16(
                    bk[kn], aq[m], (f32x4){0.f, 0.f, 0.f, 0.f}, 0, 0, 0);
#pragma unroll
            for (int m = 0; m < 2; ++m) {
                const float p0 = __builtin_amdgcn_exp2f(sm[m][0]);
                const float p1 = __builtin_amdgcn_exp2f(sm[m][1]);
                const float p2 = __builtin_amdgcn_exp2f(sm[m][2]);
                const float p3 = __builtin_amdgcn_exp2f(sm[m][3]);
                lp[m] += (p0 + p1) + (p2 + p3);
                *(uint2*)&Ps[(wq * 32 + m * 16 + fm) * PSTR + kn * 16 + kg * 4] =
                    make_uint2(pkbf(p0, p1), pkbf(p2, p3));
            }
        }

        // ---- PV: O[32q x 16d] += P[32q x 64k] * V[64k x 16d]  (wave-local)
        bf16x8 bv0 = *(const bf16x8*)&VsT[fm * VSTR2 + kg * 8];
        bf16x8 bv1 = *(const bf16x8*)&VsT[fm * VSTR2 + 32 + kg * 8];
#pragma unroll
        for (int m = 0; m < 2; ++m) {
            const int prow = wq * 32 + m * 16 + fm;
            bf16x8 ap0 = *(const bf16x8*)&Ps[prow * PSTR + kg * 8];
            bf16x8 ap1 = *(const bf16x8*)&Ps[prow * PSTR + 32 + kg * 8];
            oacc[m] = __builtin_amdgcn_mfma_f32_16x16x32_bf16(ap0, bv0, oacc[m], 0, 0, 0);
            oacc[m] = __builtin_amdgcn_mfma_f32_16x16x32_bf16(ap1, bv1, oacc[m], 0, 0, 0);
        }
    }

    // l: sum the 4 kg-group partials, transpose via LDS (wave-local)
#pragma unroll
    for (int m = 0; m < 2; ++m) {
        float v = lp[m];
        v += __shfl_xor(v, 16, 64);
        v += __shfl_xor(v, 32, 64);
        if (kg == 0) Lsh[wq * 32 + m * 16 + fm] = v;
    }

    // epilogue: C-layout rows = q (kg*4+r), cols = d (fm)
#pragma unroll
    for (int m = 0; m < 2; ++m) {
        const float4 lr = *(const float4*)&Lsh[wq * 32 + m * 16 + kg * 4];
        const int qrow = q0 + wq * 32 + m * 16 + kg * 4;
        Ob[base + (size_t)(qrow + 0) * 1024 + fm] = f2bf(oacc[m][0] / lr.x);
        Ob[base + (size_t)(qrow + 1) * 1024 + fm] = f2bf(oacc[m][1] / lr.y);
        Ob[base + (size_t)(qrow + 2) * 1024 + fm] = f2bf(oacc[m][2] / lr.z);
        Ob[base + (size_t)(qrow + 3) * 1024 + fm] = f2bf(oacc[m][3] / lr.w);
    }
}

// -------------------------------------------------------------- launch ----
extern "C" void kernel_launch(void* const* d_in, const int* in_sizes, int n_in,
                              void* d_out, int out_size, void* d_ws, size_t ws_size,
                              hipStream_t stream) {
    const float* x  = (const float*)d_in[0];
    const float* Wq = (const float*)d_in[1];
    const float* Wk = (const float*)d_in[2];
    const float* Wv = (const float*)d_in[3];
    const float* Wo = (const float*)d_in[4];
    float* out = (float*)d_out;

    const int M = 2048, N = 1024, Kd = 1024;
    const size_t MEG = 1048576;
    unsigned short* ws = (unsigned short*)d_ws;   // 28 MB high-water
    unsigned short* xb  = ws;
    unsigned short* Wqb = ws + 2 * MEG;
    unsigned short* Wkb = ws + 3 * MEG;
    unsigned short* Wvb = ws + 4 * MEG;
    unsigned short* Wob = ws + 5 * MEG;
    unsigned short* Qb  = ws + 6 * MEG;
    unsigned short* Kb  = ws + 8 * MEG;
    unsigned short* Vb  = ws + 10 * MEG;
    unsigned short* Ob  = ws + 12 * MEG;

    dim3 gc(1024, 6, 1);
    cast_to_bf16<<<gc, 256, 0, stream>>>(x, Wq, Wk, Wv, Wo, xb, Wqb, Wkb, Wvb, Wob);

    dim3 g1(N / 128, M / 64, 3);
    gemm_bt_mfma<<<g1, 256, 0, stream>>>(xb, Wqb, Wkb, Wvb, Qb, Kb, Vb, M, N, Kd, 1);

    dim3 g2(8, 128, 1);
    attn_mfma<<<g2, 256, 0, stream>>>(Qb, Kb, Vb, Ob);

    dim3 g3(N / 128, M / 64, 1);
    gemm_bt_mfma<<<g3, 256, 0, stream>>>(Ob, Wob, Wob, Wob, out, out, out, M, N, Kd, 0);
}